// Round 6
// baseline (161.162 us; speedup 1.0000x reference)
//
#include <hip/hip_runtime.h>
#include <hip/hip_bf16.h>

typedef __bf16 bf16x8 __attribute__((ext_vector_type(8)));
typedef __bf16 bf16x4 __attribute__((ext_vector_type(4)));
typedef float  f32x4  __attribute__((ext_vector_type(4)));
typedef float  f32x16 __attribute__((ext_vector_type(16)));

#define MDIM 128   // MSA rows (m)
#define NDIM 256   // residues (i/j)
#define CDIM 256   // channels
#define MIDC 32
#define OUTC 128

// lsX: [32 ij][k' = y*32+x mapped to y*36 + x], row stride 1156 bf16.
// RS/2 = 578 dw == 2 mod 32; b64 relayout writes / GEMM2 b64 reads verified
// 0-conflict in R2/R4/R5.
#define LSX_RS 1156
#define LSX_YS 36
#define LSX_BYTES (32 * LSX_RS * 2)   // 73984 B -> 2 blocks/CU

// ---------------------------------------------------------------------------
// prep: norm_inv, wb (lw||rw bf16), cbias, and owb_f packed for the 32x32x16
// B-operand (verified R5): frag (ot in 0..3, s in 0..63):
//   owb_f[((ot*64+s)*64 + lane)*8 + j] = ow[o][x*32+y]
//   with o = ot*32 + (lane&31), x = (s&1)*16 + (lane>>5)*8 + j, y = s>>1.
// ---------------------------------------------------------------------------
__global__ __launch_bounds__(256) void prep_kernel(
    const float* __restrict__ mask,
    const float* __restrict__ lw, const float* __restrict__ lb,
    const float* __restrict__ rw, const float* __restrict__ rb,
    const float* __restrict__ ow,
    __bf16* __restrict__ wb, float* __restrict__ cbias,
    __bf16* __restrict__ owb_f, float* __restrict__ norm_inv)
{
    int b = blockIdx.x, t = threadIdx.x;
    if (b < 256) {
        float s = 0.f;
        #pragma unroll 8
        for (int m = 0; m < MDIM; ++m)
            s += mask[m*NDIM + b] * mask[m*NDIM + t];
        norm_inv[b*NDIM + t] = 1.0f / (s + 1e-3f);
    } else if (b < 320) {
        int e0 = (b - 256)*2048 + t*8;
        #pragma unroll
        for (int jj = 0; jj < 8; ++jj) {
            int e = e0 + jj;
            int lane = (e >> 3) & 63;
            int s = (e >> 9) & 63;
            int ot = e >> 15;
            int o = ot*32 + (lane & 31);
            int x = (s & 1)*16 + (lane >> 5)*8 + jj;
            int y = s >> 1;
            owb_f[e] = (__bf16)ow[o*1024 + x*32 + y];
        }
    } else {
        int e0 = (b - 320)*2048 + t*8;
        #pragma unroll
        for (int j = 0; j < 8; ++j) {
            int e = e0 + j;
            int row = e >> 8, c = e & 255;
            wb[e] = (__bf16)(row < MIDC ? lw[row*CDIM + c] : rw[(row - MIDC)*CDIM + c]);
        }
        if (b == 320 && t < 64) cbias[t] = (t < MIDC) ? lb[t] : rb[t - MIDC];
    }
}

// ---------------------------------------------------------------------------
// ln_proj: unchanged (LN -> MFMA -> transpose -> fragment-linear writeback)
// grid: dim3(256, 2) x 256
// ---------------------------------------------------------------------------
__global__ __launch_bounds__(256) void ln_proj_kernel(
    const float* __restrict__ act, const float* __restrict__ mask,
    const float* __restrict__ ln_g, const float* __restrict__ ln_b,
    const __bf16* __restrict__ wb, const float* __restrict__ cbias,
    __bf16* __restrict__ left_f, __bf16* __restrict__ right_f)
{
    __shared__ __bf16 xls[64][264];
    __shared__ __bf16 T[64][72];
    int t = threadIdx.x, lane = t & 63, w = t >> 6;
    int quad = lane >> 4, l16 = lane & 15;
    int b  = blockIdx.x;
    int m0 = blockIdx.y * 64;

    float4 gv = *(const float4*)(ln_g + lane*4);
    float4 bv = *(const float4*)(ln_b + lane*4);
    const float inv_c = 1.0f / 256.0f;

    #pragma unroll 4
    for (int s = 0; s < 16; ++s) {
        int m = m0 + w*16 + s;
        float4 v = *(const float4*)(act + ((size_t)m*NDIM + b)*CDIM + lane*4);
        float sum = v.x + v.y + v.z + v.w;
        float ssq = v.x*v.x + v.y*v.y + v.z*v.z + v.w*v.w;
        #pragma unroll
        for (int d = 1; d < 64; d <<= 1) {
            sum += __shfl_xor(sum, d);
            ssq += __shfl_xor(ssq, d);
        }
        float mu   = sum * inv_c;
        float var  = ssq * inv_c - mu*mu;
        float rstd = rsqrtf(var + 1e-5f);
        bf16x4 o;
        o.x = (__bf16)((v.x - mu)*rstd*gv.x + bv.x);
        o.y = (__bf16)((v.y - mu)*rstd*gv.y + bv.y);
        o.z = (__bf16)((v.z - mu)*rstd*gv.z + bv.z);
        o.w = (__bf16)((v.w - mu)*rstd*gv.w + bv.w);
        *(bf16x4*)&xls[w*16 + s][lane*4] = o;
    }

    f32x4 acc[4] = {};
    const __bf16* arow = &xls[w*16 + l16][0];
    #pragma unroll
    for (int k0 = 0; k0 < 256; k0 += 32) {
        bf16x8 a = *(const bf16x8*)(arow + k0 + quad*8);
        #pragma unroll
        for (int tt = 0; tt < 4; ++tt) {
            bf16x8 bb = *(const bf16x8*)(wb + (size_t)(tt*16 + l16)*CDIM + k0 + quad*8);
            acc[tt] = __builtin_amdgcn_mfma_f32_16x16x32_bf16(a, bb, acc[tt], 0, 0, 0);
        }
    }

    #pragma unroll
    for (int rg = 0; rg < 4; ++rg) {
        int ml = w*16 + quad*4 + rg;
        float mval = mask[(size_t)(m0 + ml)*NDIM + b];
        #pragma unroll
        for (int tt = 0; tt < 4; ++tt) {
            int o = tt*16 + l16;
            T[o][ml] = (__bf16)(mval * (acc[tt][rg] + cbias[o]));
        }
    }
    __syncthreads();

    {
        int fl16  = t & 15;
        int r     = t >> 4;
        int q     = r & 3;
        int k0loc = (r >> 2) & 1;
        int half  = (r >> 3) & 1;
        int tile  = b*2 + half;
        int k0    = (m0 >> 5) + k0loc;
        size_t dstoff = (((size_t)tile*4 + k0)*64 + q*16 + fl16)*8;
        #pragma unroll
        for (int side = 0; side < 2; ++side) {
            int o = side*32 + half*16 + fl16;
            bf16x8 d = *(const bf16x8*)&T[o][k0loc*32 + q*8];
            __bf16* dst = side ? right_f : left_f;
            *(bf16x8*)(dst + dstoff) = d;
        }
    }
}

// ---------------------------------------------------------------------------
// outer v6: 4i x 8j (32 ij), 512 threads / 8 waves, 2 blocks/CU.
//   GEMM1 128x256x128: wave grid 2x4 (64x64 tiles), frags direct from L2
//   relayout acc1 -> lsX[ij][y*36+x] (b64, 0-conflict) -> b1
//   GEMM2 32x128x1024 via 32x32x16: wave = (ot 0..3, kh 0..1), owb once -> b2
//   kh=1 dump partials (16 KB overlay) -> b3; kh=0 reduce + epilogue.
// grid: 2048 blocks (XCD-swizzled: xcd owns an 8-wide bi strip)
// ---------------------------------------------------------------------------
__global__ __launch_bounds__(512, 4) void outer_kernel(
    const __bf16* __restrict__ left_f, const __bf16* __restrict__ right_f,
    const __bf16* __restrict__ owb_f, const float* __restrict__ ob,
    const float* __restrict__ norm_inv, float* __restrict__ out)
{
    extern __shared__ __bf16 lsX[];   // 32 * 1156 * 2 = 73984 B
    int t = threadIdx.x, lane = t & 63, w = t >> 6;   // w 0..7
    int quad = lane >> 4, l16 = lane & 15;
    int l31 = lane & 31, half = lane >> 5;

    int id = blockIdx.x;
    int xcd = id & 7, p = id >> 3;
    int bi = xcd*8 + (p & 7);   // 0..63 (4 i-values each)
    int bj = p >> 3;            // 0..31 (8 j-values each)

    // ---- GEMM1: 128x256x128; wave (wr 0..1, wc 0..3) owns 64x64 ----
    int wr = w & 1, wc = w >> 1;
    const __bf16* Af = left_f  + ((size_t)(bi*8  + wr*4)*4)*512 + lane*8;
    const __bf16* Bf = right_f + ((size_t)(bj*16 + wc*4)*4)*512 + lane*8;

    f32x4 acc1[4][4] = {};
    #pragma unroll
    for (int kk = 0; kk < 4; ++kk) {
        bf16x8 af[4], bg[4];
        #pragma unroll
        for (int tr = 0; tr < 4; ++tr) af[tr] = *(const bf16x8*)(Af + tr*2048 + kk*512);
        #pragma unroll
        for (int tc = 0; tc < 4; ++tc) bg[tc] = *(const bf16x8*)(Bf + tc*2048 + kk*512);
        #pragma unroll
        for (int tr = 0; tr < 4; ++tr)
            #pragma unroll
            for (int tc = 0; tc < 4; ++tc)
                acc1[tr][tc] = __builtin_amdgcn_mfma_f32_16x16x32_bf16(af[tr], bg[tc], acc1[tr][tc], 0, 0, 0);
    }

    // ---- GEMM2 setup + owb prefetch (loads fly across relayout + barrier) ----
    int ot = w & 3, kh = w >> 2;
    const __bf16* Ob = owb_f + ((size_t)(ot*64 + kh*32)*64 + lane)*8;
    bf16x8 bbuf0 = *(const bf16x8*)(Ob);
    bf16x8 bbuf1 = *(const bf16x8*)(Ob + 512);

    // ---- relayout: (i,x)x(j,y) -> lsX[il*8+jl][y*36 + x], b64 writes ----
    #pragma unroll
    for (int tr = 0; tr < 4; ++tr) {
        int il = wr*2 + (tr >> 1);
        int x0 = (tr & 1)*16 + quad*4;
        #pragma unroll
        for (int tc = 0; tc < 4; ++tc) {
            int jl = wc*2 + (tc >> 1);
            int y  = (tc & 1)*16 + l16;
            bf16x4 pk;
            pk.x = (__bf16)acc1[tr][tc][0];
            pk.y = (__bf16)acc1[tr][tc][1];
            pk.z = (__bf16)acc1[tr][tc][2];
            pk.w = (__bf16)acc1[tr][tc][3];
            *(bf16x4*)(lsX + (size_t)(il*8 + jl)*LSX_RS + y*LSX_YS + x0) = pk;
        }
    }
    __syncthreads();   // b1

    // ---- GEMM2: 32x32x16; wave (ot,kh): o-tile ot, k-steps kh*32..+32 ----
    f32x16 acc2 = {};
    const __bf16* Xb = lsX + (size_t)l31*LSX_RS + half*8;
    #pragma unroll 4
    for (int ss = 0; ss < 32; ++ss) {
        int s = kh*32 + ss;
        bf16x8 bb = bbuf0;
        bbuf0 = bbuf1;
        if (ss + 2 < 32) bbuf1 = *(const bf16x8*)(Ob + (ss + 2)*512);
        int xoff = (s >> 1)*LSX_YS + (s & 1)*16;
        const __bf16* ap = Xb + xoff;
        bf16x4 lo = *(const bf16x4*)(ap);
        bf16x4 hi = *(const bf16x4*)(ap + 4);
        bf16x8 a  = __builtin_shufflevector(lo, hi, 0, 1, 2, 3, 4, 5, 6, 7);
        acc2 = __builtin_amdgcn_mfma_f32_32x32x16_bf16(a, bb, acc2, 0, 0, 0);
    }
    __syncthreads();   // b2: all lsX reads done; scratch overlay safe

    // ---- K-half reduce: kh=1 dumps to scratch [ot][row*32+col] ----
    float* scr = (float*)lsX;   // 4 * 1024 * 4 B = 16 KB
    if (kh == 1) {
        int base = ot*1024;
        #pragma unroll
        for (int r = 0; r < 16; ++r) {
            int row = (r & 3) + 8*(r >> 2) + 4*half;
            scr[base + row*32 + l31] = acc2[r];
        }
    }
    __syncthreads();   // b3

    if (kh == 0) {
        int o = ot*32 + l31;
        float obv = ob[o];
        #pragma unroll
        for (int r = 0; r < 16; ++r) {
            int row = (r & 3) + 8*(r >> 2) + 4*half;   // ij in 0..31
            float v = acc2[r] + scr[ot*1024 + row*32 + l31];
            int i = bi*4 + (row >> 3), j = bj*8 + (row & 7);
            out[((size_t)(i*NDIM + j))*OUTC + o] = (v + obv) * norm_inv[i*NDIM + j];
        }
    }
}

// ---------------------------------------------------------------------------
extern "C" void kernel_launch(void* const* d_in, const int* in_sizes, int n_in,
                              void* d_out, int out_size, void* d_ws, size_t ws_size,
                              hipStream_t stream) {
    const float* act  = (const float*)d_in[0];
    const float* mask = (const float*)d_in[1];
    const float* ln_g = (const float*)d_in[2];
    const float* ln_b = (const float*)d_in[3];
    const float* lw   = (const float*)d_in[4];
    const float* lb   = (const float*)d_in[5];
    const float* rw   = (const float*)d_in[6];
    const float* rb   = (const float*)d_in[7];
    const float* ow   = (const float*)d_in[8];
    const float* ob   = (const float*)d_in[9];
    float* out = (float*)d_out;

    unsigned char* ws = (unsigned char*)d_ws;
    __bf16* left_f   = (__bf16*)(ws + 0);                 // 2 MB
    __bf16* right_f  = (__bf16*)(ws + (2u<<20));          // 2 MB
    __bf16* owb_f    = (__bf16*)(ws + (4u<<20));          // 256 KB
    float*  norm_inv = (float*) (ws + (4u<<20) + (256u<<10));   // 256 KB
    __bf16* wb       = (__bf16*)(ws + (4u<<20) + (512u<<10));   // 32 KB
    float*  cbias    = (float*) (ws + (4u<<20) + (544u<<10));   // 256 B

    hipFuncSetAttribute((const void*)outer_kernel,
                        hipFuncAttributeMaxDynamicSharedMemorySize, LSX_BYTES);

    prep_kernel<<<328, 256, 0, stream>>>(mask, lw, lb, rw, rb, ow,
                                         wb, cbias, owb_f, norm_inv);
    ln_proj_kernel<<<dim3(256, 2), 256, 0, stream>>>(act, mask, ln_g, ln_b,
                                                     wb, cbias, left_f, right_f);
    outer_kernel<<<2048, 512, LSX_BYTES, stream>>>(left_f, right_f, owb_f, ob,
                                                   norm_inv, out);
}

// Round 7
// 151.795 us; speedup vs baseline: 1.0617x; 1.0617x over previous
//
#include <hip/hip_runtime.h>
#include <hip/hip_bf16.h>

typedef __bf16 bf16x8 __attribute__((ext_vector_type(8)));
typedef __bf16 bf16x4 __attribute__((ext_vector_type(4)));
typedef float  f32x4  __attribute__((ext_vector_type(4)));
typedef float  f32x16 __attribute__((ext_vector_type(16)));

#define MDIM 128   // MSA rows (m)
#define NDIM 256   // residues (i/j)
#define CDIM 256   // channels
#define MIDC 32
#define OUTC 128

// lsX: [32 ij][k' = y*32+x mapped to y*36 + x], row stride 1156 bf16.
// RS/2 = 578 dw == 2 mod 32; b64 relayout writes / GEMM2 b64 reads verified
// 0-conflict in R2/R4/R5/R6.
#define LSX_RS 1156
#define LSX_YS 36
#define LSX_BYTES (32 * LSX_RS * 2)   // 73984 B -> 2 blocks/CU

// ---------------------------------------------------------------------------
// prep: norm_inv, wb (lw||rw bf16), cbias, and owb_f packed for the 32x32x16
// B-operand (verified R5): frag (ot in 0..3, s in 0..63):
//   owb_f[((ot*64+s)*64 + lane)*8 + j] = ow[o][x*32+y]
//   with o = ot*32 + (lane&31), x = (s&1)*16 + (lane>>5)*8 + j, y = s>>1.
// ---------------------------------------------------------------------------
__global__ __launch_bounds__(256) void prep_kernel(
    const float* __restrict__ mask,
    const float* __restrict__ lw, const float* __restrict__ lb,
    const float* __restrict__ rw, const float* __restrict__ rb,
    const float* __restrict__ ow,
    __bf16* __restrict__ wb, float* __restrict__ cbias,
    __bf16* __restrict__ owb_f, float* __restrict__ norm_inv)
{
    int b = blockIdx.x, t = threadIdx.x;
    if (b < 256) {
        float s = 0.f;
        #pragma unroll 8
        for (int m = 0; m < MDIM; ++m)
            s += mask[m*NDIM + b] * mask[m*NDIM + t];
        norm_inv[b*NDIM + t] = 1.0f / (s + 1e-3f);
    } else if (b < 320) {
        int e0 = (b - 256)*2048 + t*8;
        #pragma unroll
        for (int jj = 0; jj < 8; ++jj) {
            int e = e0 + jj;
            int lane = (e >> 3) & 63;
            int s = (e >> 9) & 63;
            int ot = e >> 15;
            int o = ot*32 + (lane & 31);
            int x = (s & 1)*16 + (lane >> 5)*8 + jj;
            int y = s >> 1;
            owb_f[e] = (__bf16)ow[o*1024 + x*32 + y];
        }
    } else {
        int e0 = (b - 320)*2048 + t*8;
        #pragma unroll
        for (int j = 0; j < 8; ++j) {
            int e = e0 + j;
            int row = e >> 8, c = e & 255;
            wb[e] = (__bf16)(row < MIDC ? lw[row*CDIM + c] : rw[(row - MIDC)*CDIM + c]);
        }
        if (b == 320 && t < 64) cbias[t] = (t < MIDC) ? lb[t] : rb[t - MIDC];
    }
}

// ---------------------------------------------------------------------------
// ln_proj: unchanged (LN -> MFMA -> transpose -> fragment-linear writeback)
// grid: dim3(256, 2) x 256
// ---------------------------------------------------------------------------
__global__ __launch_bounds__(256) void ln_proj_kernel(
    const float* __restrict__ act, const float* __restrict__ mask,
    const float* __restrict__ ln_g, const float* __restrict__ ln_b,
    const __bf16* __restrict__ wb, const float* __restrict__ cbias,
    __bf16* __restrict__ left_f, __bf16* __restrict__ right_f)
{
    __shared__ __bf16 xls[64][264];
    __shared__ __bf16 T[64][72];
    int t = threadIdx.x, lane = t & 63, w = t >> 6;
    int quad = lane >> 4, l16 = lane & 15;
    int b  = blockIdx.x;
    int m0 = blockIdx.y * 64;

    float4 gv = *(const float4*)(ln_g + lane*4);
    float4 bv = *(const float4*)(ln_b + lane*4);
    const float inv_c = 1.0f / 256.0f;

    #pragma unroll 4
    for (int s = 0; s < 16; ++s) {
        int m = m0 + w*16 + s;
        float4 v = *(const float4*)(act + ((size_t)m*NDIM + b)*CDIM + lane*4);
        float sum = v.x + v.y + v.z + v.w;
        float ssq = v.x*v.x + v.y*v.y + v.z*v.z + v.w*v.w;
        #pragma unroll
        for (int d = 1; d < 64; d <<= 1) {
            sum += __shfl_xor(sum, d);
            ssq += __shfl_xor(ssq, d);
        }
        float mu   = sum * inv_c;
        float var  = ssq * inv_c - mu*mu;
        float rstd = rsqrtf(var + 1e-5f);
        bf16x4 o;
        o.x = (__bf16)((v.x - mu)*rstd*gv.x + bv.x);
        o.y = (__bf16)((v.y - mu)*rstd*gv.y + bv.y);
        o.z = (__bf16)((v.z - mu)*rstd*gv.z + bv.z);
        o.w = (__bf16)((v.w - mu)*rstd*gv.w + bv.w);
        *(bf16x4*)&xls[w*16 + s][lane*4] = o;
    }

    f32x4 acc[4] = {};
    const __bf16* arow = &xls[w*16 + l16][0];
    #pragma unroll
    for (int k0 = 0; k0 < 256; k0 += 32) {
        bf16x8 a = *(const bf16x8*)(arow + k0 + quad*8);
        #pragma unroll
        for (int tt = 0; tt < 4; ++tt) {
            bf16x8 bb = *(const bf16x8*)(wb + (size_t)(tt*16 + l16)*CDIM + k0 + quad*8);
            acc[tt] = __builtin_amdgcn_mfma_f32_16x16x32_bf16(a, bb, acc[tt], 0, 0, 0);
        }
    }

    #pragma unroll
    for (int rg = 0; rg < 4; ++rg) {
        int ml = w*16 + quad*4 + rg;
        float mval = mask[(size_t)(m0 + ml)*NDIM + b];
        #pragma unroll
        for (int tt = 0; tt < 4; ++tt) {
            int o = tt*16 + l16;
            T[o][ml] = (__bf16)(mval * (acc[tt][rg] + cbias[o]));
        }
    }
    __syncthreads();

    {
        int fl16  = t & 15;
        int r     = t >> 4;
        int q     = r & 3;
        int k0loc = (r >> 2) & 1;
        int half  = (r >> 3) & 1;
        int tile  = b*2 + half;
        int k0    = (m0 >> 5) + k0loc;
        size_t dstoff = (((size_t)tile*4 + k0)*64 + q*16 + fl16)*8;
        #pragma unroll
        for (int side = 0; side < 2; ++side) {
            int o = side*32 + half*16 + fl16;
            bf16x8 d = *(const bf16x8*)&T[o][k0loc*32 + q*8];
            __bf16* dst = side ? right_f : left_f;
            *(bf16x8*)(dst + dstoff) = d;
        }
    }
}

// ---------------------------------------------------------------------------
// outer v7: 4i x 8j (32 ij), 512 threads / 8 waves, 2 blocks/CU.
//   stage A (32 KB into lsX region) -> b0
//   GEMM1 128x256x128: A from LDS, B direct from L2 w/ one-kk-ahead prefetch
//   preload 8-deep owb ring -> b1 (WAR on A-staging)
//   relayout acc1 -> lsX[ij][y*36+x] -> b2
//   GEMM2 32x128x1024 via 32x32x16, dual acc chains, 8-deep ring refill -> b3
//   kh=1 dump partials (16 KB overlay) -> b4; kh=0 reduce + epilogue.
// grid: 2048 blocks (XCD-swizzled)
// ---------------------------------------------------------------------------
__global__ __launch_bounds__(512, 4) void outer_kernel(
    const __bf16* __restrict__ left_f, const __bf16* __restrict__ right_f,
    const __bf16* __restrict__ owb_f, const float* __restrict__ ob,
    const float* __restrict__ norm_inv, float* __restrict__ out)
{
    extern __shared__ __bf16 lsX[];   // 32 * 1156 * 2 = 73984 B
    int t = threadIdx.x, lane = t & 63, w = t >> 6;   // w 0..7
    int quad = lane >> 4, l16 = lane & 15;
    int l31 = lane & 31, half = lane >> 5;

    int id = blockIdx.x;
    int xcd = id & 7, p = id >> 3;
    int bi = xcd*8 + (p & 7);   // 0..63 (4 i-values each)
    int bj = p >> 3;            // 0..31 (8 j-values each)

    // ---- stage A tile (32 KB) into lsX[0..16384) ----
    {
        uint4* ls4 = (uint4*)lsX;
        const uint4* gA4 = (const uint4*)(left_f + (size_t)bi*16384);
        #pragma unroll
        for (int r = 0; r < 4; ++r) ls4[r*512 + t] = gA4[r*512 + t];
    }
    __syncthreads();   // b0

    // ---- GEMM1: 128x256x128; wave (wr 0..1, wc 0..3) owns 64x64 ----
    int wr = w & 1, wc = w >> 1;
    const __bf16* lsA = lsX + (size_t)(wr*4)*2048 + lane*8;   // + tr*2048 + kk*512
    const __bf16* Bf  = right_f + ((size_t)(bj*16 + wc*4)*4)*512 + lane*8;

    bf16x8 bg[2][4];
    #pragma unroll
    for (int tc = 0; tc < 4; ++tc) bg[0][tc] = *(const bf16x8*)(Bf + tc*2048);

    f32x4 acc1[4][4] = {};
    #pragma unroll
    for (int kk = 0; kk < 4; ++kk) {
        if (kk < 3) {
            #pragma unroll
            for (int tc = 0; tc < 4; ++tc)
                bg[(kk + 1) & 1][tc] = *(const bf16x8*)(Bf + tc*2048 + (kk + 1)*512);
        }
        bf16x8 af[4];
        #pragma unroll
        for (int tr = 0; tr < 4; ++tr)
            af[tr] = *(const bf16x8*)(lsA + tr*2048 + kk*512);
        #pragma unroll
        for (int tr = 0; tr < 4; ++tr)
            #pragma unroll
            for (int tc = 0; tc < 4; ++tc)
                acc1[tr][tc] = __builtin_amdgcn_mfma_f32_16x16x32_bf16(
                    af[tr], bg[kk & 1][tc], acc1[tr][tc], 0, 0, 0);
    }

    // ---- preload 8-deep owb ring (in flight across relayout + barriers) ----
    int ot = w & 3, kh = w >> 2;
    const __bf16* Ob = owb_f + ((size_t)(ot*64 + kh*32)*64 + lane)*8;
    bf16x8 rb[8];
    #pragma unroll
    for (int r = 0; r < 8; ++r) rb[r] = *(const bf16x8*)(Ob + r*512);

    __syncthreads();   // b1: GEMM1's lsA reads done; lsX region writable

    // ---- relayout: (i,x)x(j,y) -> lsX[il*8+jl][y*36 + x], b64 writes ----
    #pragma unroll
    for (int tr = 0; tr < 4; ++tr) {
        int il = wr*2 + (tr >> 1);
        int x0 = (tr & 1)*16 + quad*4;
        #pragma unroll
        for (int tc = 0; tc < 4; ++tc) {
            int jl = wc*2 + (tc >> 1);
            int y  = (tc & 1)*16 + l16;
            bf16x4 pk;
            pk.x = (__bf16)acc1[tr][tc][0];
            pk.y = (__bf16)acc1[tr][tc][1];
            pk.z = (__bf16)acc1[tr][tc][2];
            pk.w = (__bf16)acc1[tr][tc][3];
            *(bf16x4*)(lsX + (size_t)(il*8 + jl)*LSX_RS + y*LSX_YS + x0) = pk;
        }
    }
    __syncthreads();   // b2

    // ---- GEMM2: 32x32x16; wave (ot,kh); dual acc chains; ring refill ----
    f32x16 acc2a = {}, acc2b = {};
    const __bf16* Xb = lsX + (size_t)l31*LSX_RS + half*8;
    #pragma unroll
    for (int ss = 0; ss < 32; ss += 2) {
        {
            int s = kh*32 + ss;
            int xoff = (s >> 1)*LSX_YS + (s & 1)*16;
            const __bf16* ap = Xb + xoff;
            bf16x4 lo = *(const bf16x4*)(ap);
            bf16x4 hi = *(const bf16x4*)(ap + 4);
            bf16x8 a  = __builtin_shufflevector(lo, hi, 0, 1, 2, 3, 4, 5, 6, 7);
            acc2a = __builtin_amdgcn_mfma_f32_32x32x16_bf16(a, rb[ss & 7], acc2a, 0, 0, 0);
        }
        if (ss + 8 < 32) rb[ss & 7] = *(const bf16x8*)(Ob + (ss + 8)*512);
        {
            int s = kh*32 + ss + 1;
            int xoff = (s >> 1)*LSX_YS + (s & 1)*16;
            const __bf16* ap = Xb + xoff;
            bf16x4 lo = *(const bf16x4*)(ap);
            bf16x4 hi = *(const bf16x4*)(ap + 4);
            bf16x8 a  = __builtin_shufflevector(lo, hi, 0, 1, 2, 3, 4, 5, 6, 7);
            acc2b = __builtin_amdgcn_mfma_f32_32x32x16_bf16(a, rb[(ss + 1) & 7], acc2b, 0, 0, 0);
        }
        if (ss + 9 < 32) rb[(ss + 1) & 7] = *(const bf16x8*)(Ob + (ss + 9)*512);
    }
    f32x16 acc2 = acc2a + acc2b;
    __syncthreads();   // b3: all lsX reads done; scratch overlay safe

    // ---- K-half reduce: kh=1 dumps to scratch [ot][row*32+col] ----
    float* scr = (float*)lsX;   // 4 * 1024 * 4 B = 16 KB
    if (kh == 1) {
        int base = ot*1024;
        #pragma unroll
        for (int r = 0; r < 16; ++r) {
            int row = (r & 3) + 8*(r >> 2) + 4*half;
            scr[base + row*32 + l31] = acc2[r];
        }
    }
    __syncthreads();   // b4

    if (kh == 0) {
        int o = ot*32 + l31;
        float obv = ob[o];
        #pragma unroll
        for (int r = 0; r < 16; ++r) {
            int row = (r & 3) + 8*(r >> 2) + 4*half;   // ij in 0..31
            float v = acc2[r] + scr[ot*1024 + row*32 + l31];
            int i = bi*4 + (row >> 3), j = bj*8 + (row & 7);
            out[((size_t)(i*NDIM + j))*OUTC + o] = (v + obv) * norm_inv[i*NDIM + j];
        }
    }
}

// ---------------------------------------------------------------------------
extern "C" void kernel_launch(void* const* d_in, const int* in_sizes, int n_in,
                              void* d_out, int out_size, void* d_ws, size_t ws_size,
                              hipStream_t stream) {
    const float* act  = (const float*)d_in[0];
    const float* mask = (const float*)d_in[1];
    const float* ln_g = (const float*)d_in[2];
    const float* ln_b = (const float*)d_in[3];
    const float* lw   = (const float*)d_in[4];
    const float* lb   = (const float*)d_in[5];
    const float* rw   = (const float*)d_in[6];
    const float* rb   = (const float*)d_in[7];
    const float* ow   = (const float*)d_in[8];
    const float* ob   = (const float*)d_in[9];
    float* out = (float*)d_out;

    unsigned char* ws = (unsigned char*)d_ws;
    __bf16* left_f   = (__bf16*)(ws + 0);                 // 2 MB
    __bf16* right_f  = (__bf16*)(ws + (2u<<20));          // 2 MB
    __bf16* owb_f    = (__bf16*)(ws + (4u<<20));          // 256 KB
    float*  norm_inv = (float*) (ws + (4u<<20) + (256u<<10));   // 256 KB
    __bf16* wb       = (__bf16*)(ws + (4u<<20) + (512u<<10));   // 32 KB
    float*  cbias    = (float*) (ws + (4u<<20) + (544u<<10));   // 256 B

    hipFuncSetAttribute((const void*)outer_kernel,
                        hipFuncAttributeMaxDynamicSharedMemorySize, LSX_BYTES);

    prep_kernel<<<328, 256, 0, stream>>>(mask, lw, lb, rw, rb, ow,
                                         wb, cbias, owb_f, norm_inv);
    ln_proj_kernel<<<dim3(256, 2), 256, 0, stream>>>(act, mask, ln_g, ln_b,
                                                     wb, cbias, left_f, right_f);
    outer_kernel<<<2048, 512, LSX_BYTES, stream>>>(left_f, right_f, owb_f, ob,
                                                   norm_inv, out);
}